// Round 6
// baseline (22.570 us; speedup 1.0000x reference)
//
#include <hip/hip_runtime.h>

#define K_TERMS 32   // ||B||inf * w_max <= ~6.6 -> tail 6.6^32/32! ~ 1e-23 rel

// 2-node graph:
//  1) hipMemsetAsync(out, 0, 4)  -- memset node, zeroes the fp32 accumulator
//  2) pt_fused_kernel:
//     - wave 0 of each block: register-redundant series-coefficient preamble
//       (every lane computes all of coef_k = (alpha^T B^k s)/k!, B = S + cI
//       held entirely in registers; 8 independent depth-8 FMA chains/iter,
//       ZERO cross-lane ops -> ~0.6us critical path). Lane 0 -> LDS.
//       B >= 0 entrywise => zero-cancellation series => fp32 exact enough.
//     - all waves: grid-stride Horner + __logf over w, block reduce,
//       thread 0 does ONE fp32 atomicAdd into out. No fences, no 3rd node.

__device__ __forceinline__ float pt_logdens(float x, const float* coef, float c) {
    float p = coef[K_TERMS - 1];
#pragma unroll
    for (int k = K_TERMS - 2; k >= 0; --k) p = fmaf(p, x, coef[k]);
    return __logf(p) - c * x;            // p > 0 always (nonneg coefs, x > 0)
}

__global__ __launch_bounds__(256) void pt_fused_kernel(
    const float* __restrict__ w, int n,
    const float* __restrict__ S, const float* __restrict__ alpha,
    float* __restrict__ out)
{
    __shared__ float s_coef[K_TERMS + 1];

    if (threadIdx.x < 64) {
        // ---- register-redundant preamble, wave 0 only ----
        float Sm[64];
#pragma unroll
        for (int i = 0; i < 64; ++i) Sm[i] = S[i];
        float al[8];
#pragma unroll
        for (int i = 0; i < 8; ++i) al[i] = alpha[i];

        float c = 0.0f;                              // c = max_i(-S_ii)
#pragma unroll
        for (int i = 0; i < 8; ++i) c = fmaxf(c, -Sm[i * 8 + i]);

        float B[64];
#pragma unroll
        for (int i = 0; i < 8; ++i)
#pragma unroll
            for (int j = 0; j < 8; ++j)
                B[i * 8 + j] = Sm[i * 8 + j] + ((i == j) ? c : 0.0f);

        float v[8];
#pragma unroll
        for (int i = 0; i < 8; ++i) {                // s_i = -sum_j S_ij > 0
            float rs = 0.0f;
#pragma unroll
            for (int j = 0; j < 8; ++j) rs += Sm[i * 8 + j];
            v[i] = -rs;
        }

        float coef[K_TERMS];
        {
            float d = 0.0f;
#pragma unroll
            for (int j = 0; j < 8; ++j) d = fmaf(al[j], v[j], d);
            coef[0] = d;
        }
#pragma unroll
        for (int k = 1; k < K_TERMS; ++k) {
            float nv[8];
#pragma unroll
            for (int i = 0; i < 8; ++i) {            // 8 independent chains
                float m = 0.0f;
#pragma unroll
                for (int j = 0; j < 8; ++j) m = fmaf(B[i * 8 + j], v[j], m);
                nv[i] = m * (1.0f / (float)k);       // const after unroll
            }
#pragma unroll
            for (int i = 0; i < 8; ++i) v[i] = nv[i];
            float d = 0.0f;
#pragma unroll
            for (int j = 0; j < 8; ++j) d = fmaf(al[j], v[j], d);
            coef[k] = d;
        }

        if (threadIdx.x == 0) {
#pragma unroll
            for (int k = 0; k < K_TERMS; ++k) s_coef[k] = coef[k];  // static idx
            s_coef[K_TERMS] = c;
        }
    }
    __syncthreads();

    // ---- score ----
    float coef[K_TERMS];
#pragma unroll
    for (int k = 0; k < K_TERMS; ++k) coef[k] = s_coef[k];   // LDS broadcast
    const float c = s_coef[K_TERMS];

    double local = 0.0;
    const int tid = blockIdx.x * blockDim.x + threadIdx.x;
    const int nthreads = gridDim.x * blockDim.x;
    const int n4 = n >> 2;
    const float4* w4 = (const float4*)w;
    for (int i = tid; i < n4; i += nthreads) {
        float4 wv = w4[i];
        float a4 = pt_logdens(wv.x, coef, c);
        a4 += pt_logdens(wv.y, coef, c);
        a4 += pt_logdens(wv.z, coef, c);
        a4 += pt_logdens(wv.w, coef, c);
        local += (double)a4;
    }
    for (int i = (n4 << 2) + tid; i < n; i += nthreads)      // n % 4 tail
        local += (double)pt_logdens(w[i], coef, c);

    // ---- block reduce ----
#pragma unroll
    for (int off = 32; off > 0; off >>= 1)
        local += __shfl_down(local, off, 64);

    __shared__ double red[4];
    const int wid = threadIdx.x >> 6;
    const int lane = threadIdx.x & 63;
    if (lane == 0) red[wid] = local;
    __syncthreads();
    if (threadIdx.x == 0) {
        float part = (float)(red[0] + red[1] + red[2] + red[3]);
        atomicAdd(out, part);   // fp32, one per block; error O(10) << 1.4e4
    }
}

extern "C" void kernel_launch(void* const* d_in, const int* in_sizes, int n_in,
                              void* d_out, int out_size, void* d_ws, size_t ws_size,
                              hipStream_t stream) {
    const float* w     = (const float*)d_in[0];   // [N_W]
    const float* S     = (const float*)d_in[1];   // [8,8]
    const float* alpha = (const float*)d_in[2];   // [8]
    float* out = (float*)d_out;

    const int n = in_sizes[0];
    int n4 = n >> 2;
    int blocks = (n4 + 255) / 256;
    if (blocks < 1) blocks = 1;
    if (blocks > 2048) blocks = 2048;     // grid-stride handles the rest

    hipMemsetAsync(out, 0, sizeof(float), stream);   // capturable memset node
    pt_fused_kernel<<<blocks, 256, 0, stream>>>(w, n, S, alpha, out);
}

// Round 7
// 19.781 us; speedup vs baseline: 1.1410x; 1.1410x over previous
//
#include <hip/hip_runtime.h>

#define K_TERMS 32   // ||B||inf * w_max <= ~6.6 -> tail 6.6^32/32! ~ 1e-10 rel

// 2 kernel nodes, compute-engine only (no SDMA memset, no fences, no reduce):
//  1) pt_setup: ONE wave. Every lane redundantly computes the series
//     coefficients coef_k = (alpha^T B^k s)/k! with B = S + cI held entirely
//     in registers (8 independent depth-8 FMA chains per iteration, zero
//     cross-lane ops, ~0.5us). B >= 0 entrywise -> zero-cancellation series
//     -> fp32 is exact enough. Lane 0 writes 33 floats to ws AND zeroes out.
//  2) pt_score: grid-stride Horner + __logf (coefs via uniform SGPR loads),
//     block reduce, ONE fp32 atomicAdd into out per block. Atomic-order
//     jitter <= ~15 ulp-scale vs threshold 1.4e4 (R6 measured absmax 0.0).

__global__ void pt_setup_kernel(const float* __restrict__ S,
                                const float* __restrict__ alpha,
                                float* __restrict__ coef_c,
                                float* __restrict__ out) {
    float Sm[64];
#pragma unroll
    for (int i = 0; i < 64; ++i) Sm[i] = S[i];      // uniform loads
    float al[8];
#pragma unroll
    for (int i = 0; i < 8; ++i) al[i] = alpha[i];

    float c = 0.0f;                                  // c = max_i(-S_ii)
#pragma unroll
    for (int i = 0; i < 8; ++i) c = fmaxf(c, -Sm[i * 8 + i]);

    float B[64];
#pragma unroll
    for (int i = 0; i < 8; ++i)
#pragma unroll
        for (int j = 0; j < 8; ++j)
            B[i * 8 + j] = Sm[i * 8 + j] + ((i == j) ? c : 0.0f);  // >= 0

    float v[8];
#pragma unroll
    for (int i = 0; i < 8; ++i) {                    // s_i = -sum_j S_ij > 0
        float rs = 0.0f;
#pragma unroll
        for (int j = 0; j < 8; ++j) rs += Sm[i * 8 + j];
        v[i] = -rs;
    }

    float coef[K_TERMS];
    {
        float d = 0.0f;
#pragma unroll
        for (int j = 0; j < 8; ++j) d = fmaf(al[j], v[j], d);
        coef[0] = d;
    }
#pragma unroll
    for (int k = 1; k < K_TERMS; ++k) {
        float nv[8];
#pragma unroll
        for (int i = 0; i < 8; ++i) {                // 8 independent chains
            float m = 0.0f;
#pragma unroll
            for (int j = 0; j < 8; ++j) m = fmaf(B[i * 8 + j], v[j], m);
            nv[i] = m * (1.0f / (float)k);           // const after unroll
        }
#pragma unroll
        for (int i = 0; i < 8; ++i) v[i] = nv[i];
        float d = 0.0f;
#pragma unroll
        for (int j = 0; j < 8; ++j) d = fmaf(al[j], v[j], d);
        coef[k] = d;
    }

    if (threadIdx.x == 0) {
#pragma unroll
        for (int k = 0; k < K_TERMS; ++k) coef_c[k] = coef[k];
        coef_c[K_TERMS] = c;
        out[0] = 0.0f;                               // compute-engine "memset"
    }
}

__device__ __forceinline__ float pt_logdens(float x, const float* coef, float c) {
    float p = coef[K_TERMS - 1];
#pragma unroll
    for (int k = K_TERMS - 2; k >= 0; --k) p = fmaf(p, x, coef[k]);
    return __logf(p) - c * x;                        // p > 0 always
}

__global__ __launch_bounds__(256) void pt_score_kernel(
    const float* __restrict__ w, int n,
    const float* __restrict__ coef_c,
    float* __restrict__ out)
{
    float coef[K_TERMS];
#pragma unroll
    for (int k = 0; k < K_TERMS; ++k) coef[k] = coef_c[k];  // uniform -> SGPR
    const float c = coef_c[K_TERMS];

    double local = 0.0;
    const int tid = blockIdx.x * blockDim.x + threadIdx.x;
    const int nthreads = gridDim.x * blockDim.x;
    const int n4 = n >> 2;
    const float4* w4 = (const float4*)w;
    for (int i = tid; i < n4; i += nthreads) {
        float4 wv = w4[i];
        float a4 = pt_logdens(wv.x, coef, c);
        a4 += pt_logdens(wv.y, coef, c);
        a4 += pt_logdens(wv.z, coef, c);
        a4 += pt_logdens(wv.w, coef, c);
        local += (double)a4;
    }
    for (int i = (n4 << 2) + tid; i < n; i += nthreads)     // n % 4 tail
        local += (double)pt_logdens(w[i], coef, c);

#pragma unroll
    for (int off = 32; off > 0; off >>= 1)
        local += __shfl_down(local, off, 64);

    __shared__ double red[4];
    const int wid = threadIdx.x >> 6;
    const int lane = threadIdx.x & 63;
    if (lane == 0) red[wid] = local;
    __syncthreads();
    if (threadIdx.x == 0) {
        float part = (float)(red[0] + red[1] + red[2] + red[3]);
        atomicAdd(out, part);            // one fp32 atomic per block
    }
}

extern "C" void kernel_launch(void* const* d_in, const int* in_sizes, int n_in,
                              void* d_out, int out_size, void* d_ws, size_t ws_size,
                              hipStream_t stream) {
    const float* w     = (const float*)d_in[0];   // [N_W]
    const float* S     = (const float*)d_in[1];   // [8,8]
    const float* alpha = (const float*)d_in[2];   // [8]
    float* out = (float*)d_out;

    float* coef_c = (float*)d_ws;                 // 33 floats

    const int n = in_sizes[0];
    int n4 = n >> 2;
    int blocks = (n4 + 255) / 256;
    if (blocks < 1) blocks = 1;
    if (blocks > 2048) blocks = 2048;     // grid-stride handles the rest

    pt_setup_kernel<<<1, 64, 0, stream>>>(S, alpha, coef_c, out);
    pt_score_kernel<<<blocks, 256, 0, stream>>>(w, n, coef_c, out);
}

// Round 8
// 17.168 us; speedup vs baseline: 1.3147x; 1.1522x over previous
//
#include <hip/hip_runtime.h>

#define K_TERMS 32   // ||B||inf * w_max <= ~6.6 -> tail 6.6^32/32! ~ 7e-10 rel

// 2 kernel nodes, compute-engine only, no atomics, no fences:
//  1) pt_fused: wave 0 of each block runs the REGISTER-redundant coefficient
//     preamble (every lane computes coef_k = (alpha^T B^k s)/k!, B = S + cI
//     fully in registers; 8 independent depth-8 FMA chains/iter, zero
//     cross-lane ops) -> LDS broadcast; all 4 waves then score their
//     grid-stride slice (Horner + __logf) and write ONE fp64 partial/block.
//     B >= 0 entrywise => zero-cancellation series => fp32 coefficients ok.
//  2) pt_reduce: one block sums the partials, writes float out.
// Measured costs this avoids: single-address atomics (+4-5us, R7), SDMA
// memset node (+3-4us, R6), per-block threadfence (+10us, R4), shuffle
// preamble (+3us, R2), separate setup node (+1us, R5).

__device__ __forceinline__ float pt_logdens(float x, const float* coef, float c) {
    float p = coef[K_TERMS - 1];
#pragma unroll
    for (int k = K_TERMS - 2; k >= 0; --k) p = fmaf(p, x, coef[k]);
    return __logf(p) - c * x;            // p > 0 always (nonneg coefs, x > 0)
}

__global__ __launch_bounds__(256) void pt_fused_kernel(
    const float* __restrict__ w, int n,
    const float* __restrict__ S, const float* __restrict__ alpha,
    double* __restrict__ partials)
{
    __shared__ float s_coef[K_TERMS + 1];

    if (threadIdx.x < 64) {
        // ---- register-redundant preamble (wave 0 only) ----
        float Sm[64];
#pragma unroll
        for (int i = 0; i < 64; ++i) Sm[i] = S[i];
        float al[8];
#pragma unroll
        for (int i = 0; i < 8; ++i) al[i] = alpha[i];

        float c = 0.0f;                              // c = max_i(-S_ii)
#pragma unroll
        for (int i = 0; i < 8; ++i) c = fmaxf(c, -Sm[i * 8 + i]);

        float B[64];
#pragma unroll
        for (int i = 0; i < 8; ++i)
#pragma unroll
            for (int j = 0; j < 8; ++j)
                B[i * 8 + j] = Sm[i * 8 + j] + ((i == j) ? c : 0.0f);

        float v[8];
#pragma unroll
        for (int i = 0; i < 8; ++i) {                // s_i = -sum_j S_ij > 0
            float rs = 0.0f;
#pragma unroll
            for (int j = 0; j < 8; ++j) rs += Sm[i * 8 + j];
            v[i] = -rs;
        }

        float coef[K_TERMS];
        {
            float d = 0.0f;
#pragma unroll
            for (int j = 0; j < 8; ++j) d = fmaf(al[j], v[j], d);
            coef[0] = d;
        }
#pragma unroll
        for (int k = 1; k < K_TERMS; ++k) {
            float nv[8];
#pragma unroll
            for (int i = 0; i < 8; ++i) {            // 8 independent chains
                float m = 0.0f;
#pragma unroll
                for (int j = 0; j < 8; ++j) m = fmaf(B[i * 8 + j], v[j], m);
                nv[i] = m * (1.0f / (float)k);       // const after unroll
            }
#pragma unroll
            for (int i = 0; i < 8; ++i) v[i] = nv[i];
            float d = 0.0f;
#pragma unroll
            for (int j = 0; j < 8; ++j) d = fmaf(al[j], v[j], d);
            coef[k] = d;
        }

        if (threadIdx.x == 0) {
#pragma unroll
            for (int k = 0; k < K_TERMS; ++k) s_coef[k] = coef[k];
            s_coef[K_TERMS] = c;
        }
    }
    __syncthreads();

    // ---- score ----
    float coef[K_TERMS];
#pragma unroll
    for (int k = 0; k < K_TERMS; ++k) coef[k] = s_coef[k];   // LDS broadcast
    const float c = s_coef[K_TERMS];

    double local = 0.0;
    const int tid = blockIdx.x * blockDim.x + threadIdx.x;
    const int nthreads = gridDim.x * blockDim.x;
    const int n4 = n >> 2;
    const float4* w4 = (const float4*)w;
    for (int i = tid; i < n4; i += nthreads) {
        float4 wv = w4[i];
        float a4 = pt_logdens(wv.x, coef, c);
        a4 += pt_logdens(wv.y, coef, c);
        a4 += pt_logdens(wv.z, coef, c);
        a4 += pt_logdens(wv.w, coef, c);
        local += (double)a4;
    }
    for (int i = (n4 << 2) + tid; i < n; i += nthreads)      // n % 4 tail
        local += (double)pt_logdens(w[i], coef, c);

    // ---- block reduce -> one fp64 partial per block ----
#pragma unroll
    for (int off = 32; off > 0; off >>= 1)
        local += __shfl_down(local, off, 64);

    __shared__ double red[4];
    const int wid = threadIdx.x >> 6;
    const int lane = threadIdx.x & 63;
    if (lane == 0) red[wid] = local;
    __syncthreads();
    if (threadIdx.x == 0)
        partials[blockIdx.x] = red[0] + red[1] + red[2] + red[3];
}

__global__ __launch_bounds__(512) void pt_reduce_kernel(
    const double* __restrict__ partials, int nparts, float* __restrict__ out)
{
    double local = 0.0;
    for (int i = threadIdx.x; i < nparts; i += 512) local += partials[i];
#pragma unroll
    for (int off = 32; off > 0; off >>= 1)
        local += __shfl_down(local, off, 64);

    __shared__ double red[8];
    const int wid = threadIdx.x >> 6;
    const int lane = threadIdx.x & 63;
    if (lane == 0) red[wid] = local;
    __syncthreads();
    if (threadIdx.x == 0) {
        double t = 0.0;
#pragma unroll
        for (int i = 0; i < 8; ++i) t += red[i];
        out[0] = (float)t;
    }
}

extern "C" void kernel_launch(void* const* d_in, const int* in_sizes, int n_in,
                              void* d_out, int out_size, void* d_ws, size_t ws_size,
                              hipStream_t stream) {
    const float* w     = (const float*)d_in[0];   // [N_W]
    const float* S     = (const float*)d_in[1];   // [8,8]
    const float* alpha = (const float*)d_in[2];   // [8]
    float* out = (float*)d_out;

    double* partials = (double*)d_ws;

    const int n = in_sizes[0];
    int n4 = n >> 2;
    int blocks = (n4 + 255) / 256;
    if (blocks < 1) blocks = 1;
    if (blocks > 2048) blocks = 2048;     // grid-stride handles the rest

    pt_fused_kernel<<<blocks, 256, 0, stream>>>(w, n, S, alpha, partials);
    pt_reduce_kernel<<<1, 512, 0, stream>>>(partials, blocks, out);
}

// Round 9
// 13.653 us; speedup vs baseline: 1.6530x; 1.2574x over previous
//
#include <hip/hip_runtime.h>

#define K_TERMS 24   // (||B||inf*w_max)^25/25! ~ 7.5e-5 rel tail worst-case;
                     // sum error <= ~40 << threshold 1.4e4

// R2's exact measured-best structure (15.3us), K trimmed 32->24:
//  1) pt_fused: wave 0 of each block computes coef_k = (alpha^T B^k s)/k!
//     lane-parallel (8 live lanes, shuffle matvec), B = S + cI >= 0 entrywise
//     -> zero-cancellation series -> fp32 ok. LDS broadcast; all waves score
//     their grid-stride slice (Horner + __logf); one fp64 partial per block.
//  2) pt_reduce: one block sums partials, writes float out.
// Measured taxes avoided: single-address atomics (+4-5us R7), SDMA node
// (+4us R6), threadfence (+10us R4), extra node (+1.5us R3/R5).

__device__ __forceinline__ float pt_logdens(float x, const float* coef, float c) {
    float p = coef[K_TERMS - 1];
#pragma unroll
    for (int k = K_TERMS - 2; k >= 0; --k) p = fmaf(p, x, coef[k]);
    return __logf(p) - c * x;   // p > 0 always: nonneg coefs, x > 0
}

__global__ __launch_bounds__(256) void pt_fused_kernel(
    const float* __restrict__ w, int n,
    const float* __restrict__ S, const float* __restrict__ alpha,
    double* __restrict__ partials)
{
    __shared__ float s_coef[K_TERMS];
    __shared__ float s_c;

    // ---- lane-parallel coefficient computation (wave 0; lanes 0..7 live) ----
    if (threadIdx.x < 64) {
        const int lane = threadIdx.x;
        const bool act = lane < 8;
        const float a_i = act ? alpha[lane] : 0.0f;

        float Srow[8];
        float diag = 0.0f, rs = 0.0f;
#pragma unroll
        for (int j = 0; j < 8; ++j) {
            float sv = act ? S[lane * 8 + j] : 0.0f;
            Srow[j] = sv;
            rs += sv;
            diag = (j == lane) ? sv : diag;   // select, no dynamic reg index
        }
        // c = max_i(-S_ii), reduced over the 8-lane group
        float m = -diag;
        m = fmaxf(m, __shfl_xor(m, 1, 8));
        m = fmaxf(m, __shfl_xor(m, 2, 8));
        m = fmaxf(m, __shfl_xor(m, 4, 8));
        const float c = m;

        float Brow[8];
#pragma unroll
        for (int j = 0; j < 8; ++j)
            Brow[j] = Srow[j] + ((j == lane) ? c : 0.0f);   // B >= 0 entrywise

        float v = -rs;   // s_i = -sum_j S_ij  (> 0)

        {   // k = 0: d_0 = alpha . s
            float d = a_i * v;
            d += __shfl_xor(d, 1, 8);
            d += __shfl_xor(d, 2, 8);
            d += __shfl_xor(d, 4, 8);
            if (lane == 0) s_coef[0] = d;
        }
#pragma unroll
        for (int k = 1; k < K_TERMS; ++k) {
            // v <- (B v) / k ; 8 independent shuffles then an FMA chain
            float vj[8];
#pragma unroll
            for (int j = 0; j < 8; ++j) vj[j] = __shfl(v, j, 8);
            float mm = 0.0f;
#pragma unroll
            for (int j = 0; j < 8; ++j) mm = fmaf(Brow[j], vj[j], mm);
            v = mm * (1.0f / (float)k);       // constant after unroll

            float d = a_i * v;
            d += __shfl_xor(d, 1, 8);
            d += __shfl_xor(d, 2, 8);
            d += __shfl_xor(d, 4, 8);
            if (lane == 0) s_coef[k] = d;
        }
        if (lane == 0) s_c = c;
    }
    __syncthreads();

    // ---- score slice ----
    float coef[K_TERMS];
#pragma unroll
    for (int k = 0; k < K_TERMS; ++k) coef[k] = s_coef[k];
    const float c = s_c;

    double local = 0.0;
    const int tid = blockIdx.x * blockDim.x + threadIdx.x;
    const int nthreads = gridDim.x * blockDim.x;
    const int n4 = n >> 2;
    const float4* w4 = (const float4*)w;
    for (int i = tid; i < n4; i += nthreads) {
        float4 wv = w4[i];
        float a4 = pt_logdens(wv.x, coef, c);
        a4 += pt_logdens(wv.y, coef, c);
        a4 += pt_logdens(wv.z, coef, c);
        a4 += pt_logdens(wv.w, coef, c);
        local += (double)a4;
    }
    for (int i = (n4 << 2) + tid; i < n; i += nthreads)   // n % 4 tail
        local += (double)pt_logdens(w[i], coef, c);

    // ---- block reduce -> one double partial per block ----
#pragma unroll
    for (int off = 32; off > 0; off >>= 1)
        local += __shfl_down(local, off, 64);

    __shared__ double red[4];
    const int wid = threadIdx.x >> 6;
    const int lane = threadIdx.x & 63;
    if (lane == 0) red[wid] = local;
    __syncthreads();
    if (threadIdx.x == 0)
        partials[blockIdx.x] = red[0] + red[1] + red[2] + red[3];
}

__global__ __launch_bounds__(512) void pt_reduce_kernel(
    const double* __restrict__ partials, int nparts, float* __restrict__ out)
{
    double local = 0.0;
    for (int i = threadIdx.x; i < nparts; i += 512) local += partials[i];
#pragma unroll
    for (int off = 32; off > 0; off >>= 1)
        local += __shfl_down(local, off, 64);

    __shared__ double red[8];
    const int wid = threadIdx.x >> 6;
    const int lane = threadIdx.x & 63;
    if (lane == 0) red[wid] = local;
    __syncthreads();
    if (threadIdx.x == 0) {
        double t = 0.0;
#pragma unroll
        for (int i = 0; i < 8; ++i) t += red[i];
        out[0] = (float)t;
    }
}

extern "C" void kernel_launch(void* const* d_in, const int* in_sizes, int n_in,
                              void* d_out, int out_size, void* d_ws, size_t ws_size,
                              hipStream_t stream) {
    const float* w     = (const float*)d_in[0];   // [N_W]
    const float* S     = (const float*)d_in[1];   // [8,8]
    const float* alpha = (const float*)d_in[2];   // [8]
    float* out = (float*)d_out;

    double* partials = (double*)d_ws;

    const int n = in_sizes[0];
    int n4 = n >> 2;
    int blocks = (n4 + 255) / 256;
    if (blocks < 1) blocks = 1;
    if (blocks > 2048) blocks = 2048;     // grid-stride handles the rest

    pt_fused_kernel<<<blocks, 256, 0, stream>>>(w, n, S, alpha, partials);
    pt_reduce_kernel<<<1, 512, 0, stream>>>(partials, blocks, out);
}